// Round 16
// baseline (64.437 us; speedup 1.0000x reference)
//
#include <hip/hip_runtime.h>
#include <math.h>

#define BEAMS 16
#define TMAX  2048
#define HH    32
#define DD    128
#define NSP   24              // fixed t-splits
#define TSM   88              // max timesteps per split (ceil(2048/24)=86, padded)
#define KLD   136             // staged row stride in bf16 elems (128 + 8 pad)
#define WLD   68              // Wt row stride (bf16), 64 cols + pad

typedef float          f32x4 __attribute__((ext_vector_type(4)));
typedef short          s16x8 __attribute__((ext_vector_type(8)));
typedef unsigned short u16x8 __attribute__((ext_vector_type(8)));

__device__ __forceinline__ unsigned short f2bf(float f) {
    unsigned x = __float_as_uint(f);
    return (unsigned short)((x + 0x7FFFu + ((x >> 16) & 1u)) >> 16);   // RNE
}

// assumed A/B k-permutation pi(g,j); any mismatch vs HW cancels (both operands)
__device__ __forceinline__ int kofs(int g, int j) {
    return (j < 4) ? (g * 4 + j) : (16 + g * 4 + (j - 4));
}

// ---------------------------------------------------------------------------
// Kernel 1 (r13 version): beam back-trace + dedup metadata, fixed splits,
// wave-parallel row-list emission.
// ---------------------------------------------------------------------------
__global__ __launch_bounds__(1024)
void trace_kernel(const int* __restrict__ beam_idx,
                  const int* __restrict__ offp,
                  int* __restrict__ trace_tb,
                  unsigned long long* __restrict__ slot4_g,
                  int* __restrict__ rowstart_g,
                  int* __restrict__ rows_tu,
                  int* __restrict__ ucnt_g) {
    const int off = *offp;
    const int T   = off + 1;
    const int C   = 8;
    const int NC  = (off + C - 1) / C;     // <= 256

    __shared__ int S[2][256][BEAMS];                 // 32 KB
    __shared__ unsigned short seen_s[TMAX];          // 4 KB

    const int tid = threadIdx.x;
    const int g   = tid >> 4;              // 64 groups
    const int j   = tid & 15;              // beam lane
    const int c0 = g, c1 = g + 64, c2 = g + 128, c3 = g + 192;

    // Phase A: per-chunk composed maps, 4 independent chains interleaved
    {
        int cur0 = j, cur1 = j, cur2 = j, cur3 = j;
        const int hi0 = (c0 < NC) ? min((c0 + 1) * C, off) : 0;
        const int hi1 = (c1 < NC) ? min((c1 + 1) * C, off) : 0;
        const int hi2 = (c2 < NC) ? min((c2 + 1) * C, off) : 0;
        const int hi3 = (c3 < NC) ? min((c3 + 1) * C, off) : 0;
        const int lo0 = c0 * C, lo1 = c1 * C, lo2 = c2 * C, lo3 = c3 * C;
        for (int i = 0; i < C; ++i) {
            const int ta = hi0 - 1 - i;
            if (c0 < NC && ta >= lo0) cur0 = beam_idx[ta * BEAMS + cur0];
            const int tb = hi1 - 1 - i;
            if (c1 < NC && tb >= lo1) cur1 = beam_idx[tb * BEAMS + cur1];
            const int tc = hi2 - 1 - i;
            if (c2 < NC && tc >= lo2) cur2 = beam_idx[tc * BEAMS + cur2];
            const int td = hi3 - 1 - i;
            if (c3 < NC && td >= lo3) cur3 = beam_idx[td * BEAMS + cur3];
        }
        if (c0 < NC) S[0][c0][j] = cur0;
        if (c1 < NC) S[0][c1][j] = cur1;
        if (c2 < NC) S[0][c2][j] = cur2;
        if (c3 < NC) S[0][c3][j] = cur3;
    }
    __syncthreads();

    // Phase B: suffix composition by doubling
    int rb = 0;
    for (int step = 1; step < NC; step <<= 1) {
        const int wb = rb ^ 1;
        for (int c = g; c < NC; c += 64) {
            int v;
            if (c + step < NC) v = S[rb][c][ S[rb][c + step][j] ];
            else               v = S[rb][c][j];
            S[wb][c][j] = v;
        }
        __syncthreads();
        rb = wb;
    }

    // Phase C: re-walk chunks seeded with the next chunk's suffix map
    {
        int cur0 = (c0 + 1 < NC) ? S[rb][c0 + 1][j] : j;
        int cur1 = (c1 + 1 < NC) ? S[rb][c1 + 1][j] : j;
        int cur2 = (c2 + 1 < NC) ? S[rb][c2 + 1][j] : j;
        int cur3 = (c3 + 1 < NC) ? S[rb][c3 + 1][j] : j;
        const int hi0 = (c0 < NC) ? min((c0 + 1) * C, off) : 0;
        const int hi1 = (c1 < NC) ? min((c1 + 1) * C, off) : 0;
        const int hi2 = (c2 < NC) ? min((c2 + 1) * C, off) : 0;
        const int hi3 = (c3 < NC) ? min((c3 + 1) * C, off) : 0;
        const int lo0 = c0 * C, lo1 = c1 * C, lo2 = c2 * C, lo3 = c3 * C;
        for (int i = 0; i < C; ++i) {
            const int ta = hi0 - 1 - i;
            if (c0 < NC && ta >= lo0) {
                cur0 = beam_idx[ta * BEAMS + cur0];
                trace_tb[ta * BEAMS + j] = cur0;
            }
            const int tb = hi1 - 1 - i;
            if (c1 < NC && tb >= lo1) {
                cur1 = beam_idx[tb * BEAMS + cur1];
                trace_tb[tb * BEAMS + j] = cur1;
            }
            const int tc = hi2 - 1 - i;
            if (c2 < NC && tc >= lo2) {
                cur2 = beam_idx[tc * BEAMS + cur2];
                trace_tb[tc * BEAMS + j] = cur2;
            }
            const int td = hi3 - 1 - i;
            if (c3 < NC && td >= lo3) {
                cur3 = beam_idx[td * BEAMS + cur3];
                trace_tb[td * BEAMS + j] = cur3;
            }
        }
    }
    __syncthreads();

    // ---- dedup: per t, seen-mask + 4-bit slots (rank of set bit) ----
    for (int t = tid; t < T; t += 1024) {
        if (t == off) {
            seen_s[t]  = 0xFFFFu;
            slot4_g[t] = 0xFEDCBA9876543210ull;   // slot_b = b
        } else {
            unsigned seen = 0;
            int us[16];
            #pragma unroll
            for (int b2 = 0; b2 < 16; ++b2) {
                us[b2] = trace_tb[t * BEAMS + b2];
                seen |= 1u << us[b2];
            }
            unsigned long long s4 = 0;
            #pragma unroll
            for (int b2 = 0; b2 < 16; ++b2) {
                const unsigned long long sl =
                    (unsigned long long)__popc(seen & ((1u << us[b2]) - 1u));
                s4 |= sl << (4 * b2);
            }
            seen_s[t]  = (unsigned short)seen;
            slot4_g[t] = s4;
        }
    }
    __syncthreads();

    // ---- wave-parallel row-list emission (wave wid -> splits wid, wid+16) ----
    {
        const int wid  = tid >> 6;
        const int lane = tid & 63;
        const int TS   = (T + NSP - 1) / NSP;
        for (int s = wid; s < NSP; s += 16) {
            const int ts0 = s * TS;
            const int ts1 = min(ts0 + TS, T);
            int cum = 0;
            for (int tc0 = ts0; tc0 < ts1; tc0 += 64) {
                const int t = tc0 + lane;
                const bool valid = (t < ts1);
                const unsigned seen = valid ? (unsigned)seen_s[t] : 0u;
                int x = __popc(seen);
                const int n = x;
                #pragma unroll
                for (int o = 1; o < 64; o <<= 1) {
                    const int y = __shfl_up(x, o, 64);
                    if (lane >= o) x += y;
                }
                const int base = cum + x - n;      // exclusive prefix
                if (valid) {
                    rowstart_g[t] = base;
                    int k = 0;
                    for (unsigned m = seen; m; m &= m - 1) {
                        rows_tu[s * 2048 + base + k] = t * 32 + (__ffs(m) - 1);
                        ++k;
                    }
                }
                cum += __shfl(x, 63, 64);          // wave total
            }
            if (lane == 0) ucnt_g[s] = cum;
        }
    }
}

// PV step for waves 2,3 on group parity pb: contraction over 64 u in 2 slices.
__device__ __forceinline__ void pv_step64(int pb, int w, int n16, int g4,
                                          const unsigned short (&Wt)[2][16][WLD],
                                          const unsigned short (&Vb)[2][64][KLD],
                                          f32x4 (&accO)[4]) {
    #pragma unroll
    for (int ks = 0; ks < 2; ++ks) {
        union { unsigned long long qw[2]; s16x8 v; } uw;
        uw.qw[0] = *(const unsigned long long*)(&Wt[pb][n16][ks * 32 + g4 * 4]);
        uw.qw[1] = *(const unsigned long long*)(&Wt[pb][n16][ks * 32 + 16 + g4 * 4]);
        #pragma unroll
        for (int dt = 0; dt < 4; ++dt) {
            const int d = ((w - 2) * 4 + dt) * 16 + n16;
            s16x8 bf;
            #pragma unroll
            for (int jj = 0; jj < 8; ++jj)
                bf[jj] = (short)Vb[pb][ks * 32 + kofs(g4, jj)][d];
            accO[dt] = __builtin_amdgcn_mfma_f32_16x16x32_bf16(uw.v, bf, accO[dt], 0, 0, 0);
        }
    }
}

// ---------------------------------------------------------------------------
// Kernel 2: MFMA flash-decode over unique rows, wave-pipelined, 64-ROW GROUPS.
// Block = (h, fixed split). Per 64-row group g (2 barriers each):
//   ds_write staged regs -> buf[g&1]; prefetch g+1 loads (16 float4/thread);
//   barrier; waves 0,1: QK^T(g) 2 u-tiles each + W-fill -> Wt[g&1]
//   (in parallel with) waves 2,3: PV(g-1); barrier.
// Epilogue: waves 2,3 do PV(G-1). 2 blocks/CU (~79 KB LDS).
// ---------------------------------------------------------------------------
__global__ __launch_bounds__(256, 2)
void attn_split_kernel(const float* __restrict__ q,
                       const float* __restrict__ knew,
                       const float* __restrict__ vnew,
                       const float* __restrict__ kc,
                       const float* __restrict__ vc,
                       const float* __restrict__ mask,
                       const unsigned long long* __restrict__ slot4_g,
                       const int* __restrict__ rowstart_g,
                       const int* __restrict__ rows_tu,
                       const int* __restrict__ ucnt_g,
                       const int* __restrict__ offp,
                       float* __restrict__ pl,
                       float* __restrict__ po) {
    const int off = *offp;
    const int T   = off + 1;
    const int TS  = (T + NSP - 1) / NSP;
    const int h   = blockIdx.x / NSP;
    const int s   = blockIdx.x - h * NSP;
    const int ts0 = s * TS;
    const int ts1 = min(ts0 + TS, T);
    const int nts = ts1 - ts0;
    const int U   = ucnt_g[s];
    const int G   = (U + 63) >> 6;

    __shared__ unsigned short Kb[2][64][KLD];      // 34,816 B
    __shared__ unsigned short Vb[2][64][KLD];      // 34,816 B
    __shared__ unsigned short Wt[2][16][WLD];      //  4,352 B
    __shared__ float mask_s[16][TSM];              //  5,632 B
    __shared__ unsigned long long slot4_s[TSM];    //    704 B
    __shared__ int   rbase_s[TSM];                 //    352 B
    __shared__ float ls[2][16];                    //    128 B

    const int tid = threadIdx.x;
    const int w   = tid >> 6;                      // wave 0..3
    const int l   = tid & 63;
    const int n16 = l & 15;
    const int g4  = l >> 4;

    // ---- metadata staging ----
    for (int i = tid; i < 16 * TSM; i += 256) {
        const int bb = i / TSM, tt = i - bb * TSM;
        mask_s[bb][tt] = (tt < nts) ? mask[(size_t)bb * T + ts0 + tt] : 0.f;
    }
    for (int i = tid; i < nts; i += 256) {
        slot4_s[i] = slot4_g[ts0 + i];
        rbase_s[i] = rowstart_g[ts0 + i];
    }

    // ---- Q B-fragments (bf16, pre-scaled), one per 32-d chunk ----
    const float inv_scale = 0.08838834764831843f;  // 1/sqrt(128)
    s16x8 qf[4];
    {
        const float* qp = q + ((size_t)(n16 * HH + h)) * DD;
        #pragma unroll
        for (int c = 0; c < 4; ++c) {
            const int base = 32 * c + g4 * 4;
            const float4 lo = *(const float4*)(qp + base);
            const float4 hi = *(const float4*)(qp + base + 16);
            qf[c][0] = (short)f2bf(lo.x * inv_scale);
            qf[c][1] = (short)f2bf(lo.y * inv_scale);
            qf[c][2] = (short)f2bf(lo.z * inv_scale);
            qf[c][3] = (short)f2bf(lo.w * inv_scale);
            qf[c][4] = (short)f2bf(hi.x * inv_scale);
            qf[c][5] = (short)f2bf(hi.y * inv_scale);
            qf[c][6] = (short)f2bf(hi.z * inv_scale);
            qf[c][7] = (short)f2bf(hi.w * inv_scale);
        }
    }

    // staging roles: thread handles rows r1, r1+16, r1+32, r1+48 of each group
    const int r1 = tid >> 4;
    const int cc = tid & 15;
    float4 k0a, k0b, v0a, v0b, k1a, k1b, v1a, v1b;
    float4 k2a, k2b, v2a, v2b, k3a, k3b, v3a, v3b;

#define LOADR(UU, KA, KB, VA, VB)                                            \
    {                                                                        \
        const int uu = (UU);                                                 \
        const int tu = (uu < U) ? rows_tu[s * 2048 + uu] : 0;                \
        const int t_ = tu >> 5, u_ = tu & 31;                                \
        const float *ks, *vs;                                                \
        if (t_ < off) {                                                      \
            const size_t ro = ((size_t)(t_ * BEAMS + u_) * HH + h) * DD;     \
            ks = kc + ro; vs = vc + ro;                                      \
        } else {                                                             \
            const size_t ro = ((size_t)u_ * HH + h) * DD;                    \
            ks = knew + ro; vs = vnew + ro;                                  \
        }                                                                    \
        KA = *(const float4*)(ks + cc * 8);                                  \
        KB = *(const float4*)(ks + cc * 8 + 4);                              \
        VA = *(const float4*)(vs + cc * 8);                                  \
        VB = *(const float4*)(vs + cc * 8 + 4);                              \
    }

#define PACK8(DST, A, B)                                                     \
    {                                                                        \
        u16x8 p_;                                                            \
        p_[0] = f2bf(A.x); p_[1] = f2bf(A.y); p_[2] = f2bf(A.z);             \
        p_[3] = f2bf(A.w); p_[4] = f2bf(B.x); p_[5] = f2bf(B.y);             \
        p_[6] = f2bf(B.z); p_[7] = f2bf(B.w);                                \
        *(u16x8*)(DST) = p_;                                                 \
    }

    f32x4 accO[4];
    #pragma unroll
    for (int dt = 0; dt < 4; ++dt) accO[dt] = (f32x4){0.f, 0.f, 0.f, 0.f};
    float l_acc = 0.f;

    __syncthreads();   // metadata staged

    if (G > 0) {
        LOADR(0 * 64 + r1,      k0a, k0b, v0a, v0b)
        LOADR(0 * 64 + r1 + 16, k1a, k1b, v1a, v1b)
        LOADR(0 * 64 + r1 + 32, k2a, k2b, v2a, v2b)
        LOADR(0 * 64 + r1 + 48, k3a, k3b, v3a, v3b)
    }

    for (int g = 0; g < G; ++g) {
        const int buf = g & 1;
        PACK8(&Kb[buf][r1][cc * 8],      k0a, k0b)
        PACK8(&Vb[buf][r1][cc * 8],      v0a, v0b)
        PACK8(&Kb[buf][r1 + 16][cc * 8], k1a, k1b)
        PACK8(&Vb[buf][r1 + 16][cc * 8], v1a, v1b)
        PACK8(&Kb[buf][r1 + 32][cc * 8], k2a, k2b)
        PACK8(&Vb[buf][r1 + 32][cc * 8], v2a, v2b)
        PACK8(&Kb[buf][r1 + 48][cc * 8], k3a, k3b)
        PACK8(&Vb[buf][r1 + 48][cc * 8], v3a, v3b)
        if (g + 1 < G) {
            LOADR((g + 1) * 64 + r1,      k0a, k0b, v0a, v0b)
            LOADR((g + 1) * 64 + r1 + 16, k1a, k1b, v1a, v1b)
            LOADR((g + 1) * 64 + r1 + 32, k2a, k2b, v2a, v2b)
            LOADR((g + 1) * 64 + r1 + 48, k3a, k3b, v3a, v3b)
        }
        __syncthreads();   // barrier1: group g staged

        if (w < 2) {
            // ---- QK^T(g): 2 u-tiles per wave + W-fill -> Wt[buf] ----
            #pragma unroll
            for (int ut2 = 0; ut2 < 2; ++ut2) {
                const int ut = w * 2 + ut2;
                f32x4 acc = {0.f, 0.f, 0.f, 0.f};
                const unsigned short* krow = &Kb[buf][ut * 16 + n16][0];
                #pragma unroll
                for (int c = 0; c < 4; ++c) {
                    const unsigned short* ka = krow + 32 * c + g4 * 4;
                    union { unsigned long long qw[2]; s16x8 v; } ua;
                    ua.qw[0] = *(const unsigned long long*)(ka);
                    ua.qw[1] = *(const unsigned long long*)(ka + 16);
                    acc = __builtin_amdgcn_mfma_f32_16x16x32_bf16(ua.v, qf[c], acc, 0, 0, 0);
                }
                unsigned short wout[4];
                #pragma unroll
                for (int r = 0; r < 4; ++r) {
                    const int u_loc = g * 64 + ut * 16 + g4 * 4 + r;
                    const bool valid = (u_loc < U);
                    const int tu = valid ? rows_tu[s * 2048 + u_loc] : 0;
                    const int t_ = tu >> 5;
                    int tt = t_ - ts0;
                    tt = (tt < 0) ? 0 : tt;
                    const unsigned long long s4 = slot4_s[tt];
                    const int myslot = (int)((s4 >> (4 * n16)) & 15);
                    const int expsl  = u_loc - rbase_s[tt];
                    const bool match = valid && (myslot == expsl);
                    const float sc = acc[r] + mask_s[n16][tt];
                    const float wv = match ? __expf(sc) : 0.f;
                    l_acc += wv;
                    wout[r] = f2bf(wv);
                }
                const int wc = ut * 16 + g4 * 4;
                *(unsigned*)&Wt[buf][n16][wc]     = (unsigned)wout[0] | ((unsigned)wout[1] << 16);
                *(unsigned*)&Wt[buf][n16][wc + 2] = (unsigned)wout[2] | ((unsigned)wout[3] << 16);
            }
        } else if (g > 0) {
            // ---- PV(g-1) from the other parity ----
            pv_step64(buf ^ 1, w, n16, g4, Wt, Vb, accO);
        }
        __syncthreads();   // barrier2: Wt[buf] ready; PV(g-1) done
    }
    if (G > 0 && w >= 2) {
        pv_step64((G - 1) & 1, w, n16, g4, Wt, Vb, accO);
    }
#undef LOADR
#undef PACK8

    // ---- l reduction (waves 0,1) ----
    if (w < 2) {
        l_acc += __shfl_xor(l_acc, 16, 64);
        l_acc += __shfl_xor(l_acc, 32, 64);
        if (l < 16) ls[w][n16] = l_acc;
    }
    __syncthreads();
    if (tid < 16)
        pl[((size_t)tid * HH + h) * NSP + s] = ls[0][tid] + ls[1][tid];

    // ---- O partial write (C/D layout: col=n16=d-local, row=g4*4+r=b) ----
    if (w >= 2) {
        #pragma unroll
        for (int dt = 0; dt < 4; ++dt) {
            const int d = ((w - 2) * 4 + dt) * 16 + n16;
            #pragma unroll
            for (int r = 0; r < 4; ++r) {
                const int b = g4 * 4 + r;
                po[((size_t)(b * HH + h) * NSP + s) * DD + d] = accO[dt][r];
            }
        }
    }
}

// ---------------------------------------------------------------------------
// Kernel 3: merge the NSP partials per (b,h) — plain sum + normalize.
// ---------------------------------------------------------------------------
__global__ __launch_bounds__(128)
void attn_reduce_kernel(const float* __restrict__ pl,
                        const float* __restrict__ po,
                        float* __restrict__ out) {
    const int bh = blockIdx.x;
    const int d  = threadIdx.x;
    float l = 0.f, o = 0.f;
    #pragma unroll 8
    for (int s = 0; s < NSP; ++s) {
        l += pl[(size_t)bh * NSP + s];
        o += po[((size_t)bh * NSP + s) * DD + d];
    }
    out[(size_t)bh * DD + d] = o / l;
}

// ---------------------------------------------------------------------------
extern "C" void kernel_launch(void* const* d_in, const int* in_sizes, int n_in,
                              void* d_out, int out_size, void* d_ws, size_t ws_size,
                              hipStream_t stream) {
    const float* q    = (const float*)d_in[0];
    const float* knew = (const float*)d_in[1];
    const float* vnew = (const float*)d_in[2];
    const float* kc   = (const float*)d_in[3];
    const float* vc   = (const float*)d_in[4];
    const int*   bidx = (const int*)d_in[5];
    const float* mask = (const float*)d_in[6];
    const int*   offp = (const int*)d_in[7];

    char* ws = (char*)d_ws;
    int*                trace_tb = (int*)(ws);                          // 131072
    unsigned long long* slot4    = (unsigned long long*)(ws + 131072);  // 16384
    int*                rowstart = (int*)(ws + 147456);                 // 8192
    int*                rows_tu  = (int*)(ws + 155648);                 // 196608
    int*                ucnt_g   = (int*)(ws + 352256);                 // 512
    float*              pl       = (float*)(ws + 352768);               // 49152
    float*              po       = (float*)(ws + 401920);               // 6291456

    hipLaunchKernelGGL(trace_kernel, dim3(1), dim3(1024), 0, stream,
                       bidx, offp, trace_tb, slot4, rowstart, rows_tu,
                       ucnt_g);
    hipLaunchKernelGGL(attn_split_kernel, dim3(HH * NSP), dim3(256), 0, stream,
                       q, knew, vnew, kc, vc, mask,
                       slot4, rowstart, rows_tu, ucnt_g, offp,
                       pl, po);
    hipLaunchKernelGGL(attn_reduce_kernel, dim3(BEAMS * HH), dim3(128), 0, stream,
                       pl, po, (float*)d_out);
}

// Round 17
// 52.807 us; speedup vs baseline: 1.2202x; 1.2202x over previous
//
#include <hip/hip_runtime.h>
#include <math.h>

#define BEAMS 16
#define TMAX  2048
#define HH    32
#define DD    128
#define NSP   24              // fixed t-splits
#define TSM   88              // max timesteps per split (ceil(2048/24)=86, padded)
#define KLD   132             // staged row stride in bf16 elems (128 + 4 pad)
#define WLD   40              // Wt row stride (bf16)

typedef float          f32x4 __attribute__((ext_vector_type(4)));
typedef short          s16x8 __attribute__((ext_vector_type(8)));
typedef unsigned short u16x8 __attribute__((ext_vector_type(8)));

__device__ __forceinline__ unsigned short f2bf(float f) {
    unsigned x = __float_as_uint(f);
    return (unsigned short)((x + 0x7FFFu + ((x >> 16) & 1u)) >> 16);   // RNE
}
__device__ __forceinline__ float bf2f(unsigned short v) {
    return __uint_as_float((unsigned)v << 16);
}

// assumed A/B k-permutation pi(g,j); any mismatch vs HW cancels (both operands)
__device__ __forceinline__ int kofs(int g, int j) {
    return (j < 4) ? (g * 4 + j) : (16 + g * 4 + (j - 4));
}

// ---------------------------------------------------------------------------
// Kernel 1 (r13): beam back-trace + dedup metadata, fixed splits,
// wave-parallel row-list emission.
// ---------------------------------------------------------------------------
__global__ __launch_bounds__(1024)
void trace_kernel(const int* __restrict__ beam_idx,
                  const int* __restrict__ offp,
                  int* __restrict__ trace_tb,
                  unsigned long long* __restrict__ slot4_g,
                  int* __restrict__ rowstart_g,
                  int* __restrict__ rows_tu,
                  int* __restrict__ ucnt_g) {
    const int off = *offp;
    const int T   = off + 1;
    const int C   = 8;
    const int NC  = (off + C - 1) / C;     // <= 256

    __shared__ int S[2][256][BEAMS];                 // 32 KB
    __shared__ unsigned short seen_s[TMAX];          // 4 KB

    const int tid = threadIdx.x;
    const int g   = tid >> 4;              // 64 groups
    const int j   = tid & 15;              // beam lane
    const int c0 = g, c1 = g + 64, c2 = g + 128, c3 = g + 192;

    // Phase A: per-chunk composed maps, 4 independent chains interleaved
    {
        int cur0 = j, cur1 = j, cur2 = j, cur3 = j;
        const int hi0 = (c0 < NC) ? min((c0 + 1) * C, off) : 0;
        const int hi1 = (c1 < NC) ? min((c1 + 1) * C, off) : 0;
        const int hi2 = (c2 < NC) ? min((c2 + 1) * C, off) : 0;
        const int hi3 = (c3 < NC) ? min((c3 + 1) * C, off) : 0;
        const int lo0 = c0 * C, lo1 = c1 * C, lo2 = c2 * C, lo3 = c3 * C;
        for (int i = 0; i < C; ++i) {
            const int ta = hi0 - 1 - i;
            if (c0 < NC && ta >= lo0) cur0 = beam_idx[ta * BEAMS + cur0];
            const int tb = hi1 - 1 - i;
            if (c1 < NC && tb >= lo1) cur1 = beam_idx[tb * BEAMS + cur1];
            const int tc = hi2 - 1 - i;
            if (c2 < NC && tc >= lo2) cur2 = beam_idx[tc * BEAMS + cur2];
            const int td = hi3 - 1 - i;
            if (c3 < NC && td >= lo3) cur3 = beam_idx[td * BEAMS + cur3];
        }
        if (c0 < NC) S[0][c0][j] = cur0;
        if (c1 < NC) S[0][c1][j] = cur1;
        if (c2 < NC) S[0][c2][j] = cur2;
        if (c3 < NC) S[0][c3][j] = cur3;
    }
    __syncthreads();

    // Phase B: suffix composition by doubling
    int rb = 0;
    for (int step = 1; step < NC; step <<= 1) {
        const int wb = rb ^ 1;
        for (int c = g; c < NC; c += 64) {
            int v;
            if (c + step < NC) v = S[rb][c][ S[rb][c + step][j] ];
            else               v = S[rb][c][j];
            S[wb][c][j] = v;
        }
        __syncthreads();
        rb = wb;
    }

    // Phase C: re-walk chunks seeded with the next chunk's suffix map
    {
        int cur0 = (c0 + 1 < NC) ? S[rb][c0 + 1][j] : j;
        int cur1 = (c1 + 1 < NC) ? S[rb][c1 + 1][j] : j;
        int cur2 = (c2 + 1 < NC) ? S[rb][c2 + 1][j] : j;
        int cur3 = (c3 + 1 < NC) ? S[rb][c3 + 1][j] : j;
        const int hi0 = (c0 < NC) ? min((c0 + 1) * C, off) : 0;
        const int hi1 = (c1 < NC) ? min((c1 + 1) * C, off) : 0;
        const int hi2 = (c2 < NC) ? min((c2 + 1) * C, off) : 0;
        const int hi3 = (c3 < NC) ? min((c3 + 1) * C, off) : 0;
        const int lo0 = c0 * C, lo1 = c1 * C, lo2 = c2 * C, lo3 = c3 * C;
        for (int i = 0; i < C; ++i) {
            const int ta = hi0 - 1 - i;
            if (c0 < NC && ta >= lo0) {
                cur0 = beam_idx[ta * BEAMS + cur0];
                trace_tb[ta * BEAMS + j] = cur0;
            }
            const int tb = hi1 - 1 - i;
            if (c1 < NC && tb >= lo1) {
                cur1 = beam_idx[tb * BEAMS + cur1];
                trace_tb[tb * BEAMS + j] = cur1;
            }
            const int tc = hi2 - 1 - i;
            if (c2 < NC && tc >= lo2) {
                cur2 = beam_idx[tc * BEAMS + cur2];
                trace_tb[tc * BEAMS + j] = cur2;
            }
            const int td = hi3 - 1 - i;
            if (c3 < NC && td >= lo3) {
                cur3 = beam_idx[td * BEAMS + cur3];
                trace_tb[td * BEAMS + j] = cur3;
            }
        }
    }
    __syncthreads();

    // ---- dedup: per t, seen-mask + 4-bit slots (rank of set bit) ----
    for (int t = tid; t < T; t += 1024) {
        if (t == off) {
            seen_s[t]  = 0xFFFFu;
            slot4_g[t] = 0xFEDCBA9876543210ull;   // slot_b = b
        } else {
            unsigned seen = 0;
            int us[16];
            #pragma unroll
            for (int b2 = 0; b2 < 16; ++b2) {
                us[b2] = trace_tb[t * BEAMS + b2];
                seen |= 1u << us[b2];
            }
            unsigned long long s4 = 0;
            #pragma unroll
            for (int b2 = 0; b2 < 16; ++b2) {
                const unsigned long long sl =
                    (unsigned long long)__popc(seen & ((1u << us[b2]) - 1u));
                s4 |= sl << (4 * b2);
            }
            seen_s[t]  = (unsigned short)seen;
            slot4_g[t] = s4;
        }
    }
    __syncthreads();

    // ---- wave-parallel row-list emission (wave wid -> splits wid, wid+16) ----
    {
        const int wid  = tid >> 6;
        const int lane = tid & 63;
        const int TS   = (T + NSP - 1) / NSP;
        for (int s = wid; s < NSP; s += 16) {
            const int ts0 = s * TS;
            const int ts1 = min(ts0 + TS, T);
            int cum = 0;
            for (int tc0 = ts0; tc0 < ts1; tc0 += 64) {
                const int t = tc0 + lane;
                const bool valid = (t < ts1);
                const unsigned seen = valid ? (unsigned)seen_s[t] : 0u;
                int x = __popc(seen);
                const int n = x;
                #pragma unroll
                for (int o = 1; o < 64; o <<= 1) {
                    const int y = __shfl_up(x, o, 64);
                    if (lane >= o) x += y;
                }
                const int base = cum + x - n;      // exclusive prefix
                if (valid) {
                    rowstart_g[t] = base;
                    int k = 0;
                    for (unsigned m = seen; m; m &= m - 1) {
                        rows_tu[s * 2048 + base + k] = t * 32 + (__ffs(m) - 1);
                        ++k;
                    }
                }
                cum += __shfl(x, 63, 64);          // wave total
            }
            if (lane == 0) ucnt_g[s] = cum;
        }
    }
}

// PV step for waves 2,3 on group parity pb (reads Wt[pb], Vb[pb])
__device__ __forceinline__ void pv_step(int pb, int w, int n16, int g4,
                                        const unsigned short (&Wt)[2][16][WLD],
                                        const unsigned short (&Vb)[2][32][KLD],
                                        f32x4 (&accO)[4]) {
    union { unsigned long long qw[2]; s16x8 v; } uw;
    uw.qw[0] = *(const unsigned long long*)(&Wt[pb][n16][g4 * 4]);
    uw.qw[1] = *(const unsigned long long*)(&Wt[pb][n16][16 + g4 * 4]);
    #pragma unroll
    for (int dt = 0; dt < 4; ++dt) {
        const int d = ((w - 2) * 4 + dt) * 16 + n16;
        s16x8 bf;
        #pragma unroll
        for (int jj = 0; jj < 8; ++jj)
            bf[jj] = (short)Vb[pb][kofs(g4, jj)][d];
        accO[dt] = __builtin_amdgcn_mfma_f32_16x16x32_bf16(uw.v, bf, accO[dt], 0, 0, 0);
    }
}

// ---------------------------------------------------------------------------
// Kernel 2: MFMA flash-decode over unique rows, wave-pipelined (r13 core),
// LDS trimmed to 40.4 KB (KLD 132, bf16 mask) -> 4 blocks/CU.
// ---------------------------------------------------------------------------
__global__ __launch_bounds__(256, 4)
void attn_split_kernel(const float* __restrict__ q,
                       const float* __restrict__ knew,
                       const float* __restrict__ vnew,
                       const float* __restrict__ kc,
                       const float* __restrict__ vc,
                       const float* __restrict__ mask,
                       const unsigned long long* __restrict__ slot4_g,
                       const int* __restrict__ rowstart_g,
                       const int* __restrict__ rows_tu,
                       const int* __restrict__ ucnt_g,
                       const int* __restrict__ offp,
                       float* __restrict__ pl,
                       float* __restrict__ po) {
    const int off = *offp;
    const int T   = off + 1;
    const int TS  = (T + NSP - 1) / NSP;
    const int h   = blockIdx.x / NSP;
    const int s   = blockIdx.x - h * NSP;
    const int ts0 = s * TS;
    const int ts1 = min(ts0 + TS, T);
    const int nts = ts1 - ts0;
    const int U   = ucnt_g[s];
    const int G   = (U + 31) >> 5;

    __shared__ unsigned short Kb[2][32][KLD];      // 16,896 B
    __shared__ unsigned short Vb[2][32][KLD];      // 16,896 B
    __shared__ unsigned short Wt[2][16][WLD];      //  2,560 B
    __shared__ unsigned short mask_s[16][TSM];     //  2,816 B (bf16)
    __shared__ unsigned long long slot4_s[TSM];    //    704 B
    __shared__ int   rbase_s[TSM];                 //    352 B
    __shared__ float ls[2][16];                    //    128 B

    const int tid = threadIdx.x;
    const int w   = tid >> 6;                      // wave 0..3
    const int l   = tid & 63;
    const int n16 = l & 15;
    const int g4  = l >> 4;

    // ---- metadata staging ----
    for (int i = tid; i < 16 * TSM; i += 256) {
        const int bb = i / TSM, tt = i - bb * TSM;
        mask_s[bb][tt] = (tt < nts) ? f2bf(mask[(size_t)bb * T + ts0 + tt]) : 0;
    }
    for (int i = tid; i < nts; i += 256) {
        slot4_s[i] = slot4_g[ts0 + i];
        rbase_s[i] = rowstart_g[ts0 + i];
    }

    // ---- Q B-fragments (bf16, pre-scaled), one per 32-d chunk ----
    const float inv_scale = 0.08838834764831843f;  // 1/sqrt(128)
    s16x8 qf[4];
    {
        const float* qp = q + ((size_t)(n16 * HH + h)) * DD;
        #pragma unroll
        for (int c = 0; c < 4; ++c) {
            const int base = 32 * c + g4 * 4;
            const float4 lo = *(const float4*)(qp + base);
            const float4 hi = *(const float4*)(qp + base + 16);
            qf[c][0] = (short)f2bf(lo.x * inv_scale);
            qf[c][1] = (short)f2bf(lo.y * inv_scale);
            qf[c][2] = (short)f2bf(lo.z * inv_scale);
            qf[c][3] = (short)f2bf(lo.w * inv_scale);
            qf[c][4] = (short)f2bf(hi.x * inv_scale);
            qf[c][5] = (short)f2bf(hi.y * inv_scale);
            qf[c][6] = (short)f2bf(hi.z * inv_scale);
            qf[c][7] = (short)f2bf(hi.w * inv_scale);
        }
    }

    // staging roles: thread handles rows r1 and r1+16 of each 32-row group
    const int r1 = tid >> 4;
    const int cc = tid & 15;
    float4 sk1a, sk1b, sv1a, sv1b, sk2a, sk2b, sv2a, sv2b;

#define LOADR(UU, KA, KB, VA, VB)                                            \
    {                                                                        \
        const int uu = (UU);                                                 \
        const int tu = (uu < U) ? rows_tu[s * 2048 + uu] : 0;                \
        const int t_ = tu >> 5, u_ = tu & 31;                                \
        const float *ks, *vs;                                                \
        if (t_ < off) {                                                      \
            const size_t ro = ((size_t)(t_ * BEAMS + u_) * HH + h) * DD;     \
            ks = kc + ro; vs = vc + ro;                                      \
        } else {                                                             \
            const size_t ro = ((size_t)u_ * HH + h) * DD;                    \
            ks = knew + ro; vs = vnew + ro;                                  \
        }                                                                    \
        KA = *(const float4*)(ks + cc * 8);                                  \
        KB = *(const float4*)(ks + cc * 8 + 4);                              \
        VA = *(const float4*)(vs + cc * 8);                                  \
        VB = *(const float4*)(vs + cc * 8 + 4);                              \
    }

#define PACK8(DST, A, B)                                                     \
    {                                                                        \
        u16x8 p_;                                                            \
        p_[0] = f2bf(A.x); p_[1] = f2bf(A.y); p_[2] = f2bf(A.z);             \
        p_[3] = f2bf(A.w); p_[4] = f2bf(B.x); p_[5] = f2bf(B.y);             \
        p_[6] = f2bf(B.z); p_[7] = f2bf(B.w);                                \
        *(u16x8*)(DST) = p_;                                                 \
    }

    f32x4 accO[4];
    #pragma unroll
    for (int dt = 0; dt < 4; ++dt) accO[dt] = (f32x4){0.f, 0.f, 0.f, 0.f};
    float l_acc = 0.f;

    __syncthreads();   // metadata staged

    if (G > 0) { LOADR(0 * 32 + r1, sk1a, sk1b, sv1a, sv1b)
                 LOADR(0 * 32 + r1 + 16, sk2a, sk2b, sv2a, sv2b) }

    for (int g = 0; g < G; ++g) {
        const int buf = g & 1;
        PACK8(&Kb[buf][r1][cc * 8],      sk1a, sk1b)
        PACK8(&Vb[buf][r1][cc * 8],      sv1a, sv1b)
        PACK8(&Kb[buf][r1 + 16][cc * 8], sk2a, sk2b)
        PACK8(&Vb[buf][r1 + 16][cc * 8], sv2a, sv2b)
        if (g + 1 < G) {
            LOADR((g + 1) * 32 + r1, sk1a, sk1b, sv1a, sv1b)
            LOADR((g + 1) * 32 + r1 + 16, sk2a, sk2b, sv2a, sv2b)
        }
        __syncthreads();   // barrier1: group g staged

        if (w < 2) {
            // ---- QK^T(g) + W-fill -> Wt[buf] ----
            f32x4 acc = {0.f, 0.f, 0.f, 0.f};
            const unsigned short* krow = &Kb[buf][w * 16 + n16][0];
            #pragma unroll
            for (int c = 0; c < 4; ++c) {
                const unsigned short* ka = krow + 32 * c + g4 * 4;
                union { unsigned long long qw[2]; s16x8 v; } ua;
                ua.qw[0] = *(const unsigned long long*)(ka);
                ua.qw[1] = *(const unsigned long long*)(ka + 16);
                acc = __builtin_amdgcn_mfma_f32_16x16x32_bf16(ua.v, qf[c], acc, 0, 0, 0);
            }
            unsigned short wout[4];
            #pragma unroll
            for (int r = 0; r < 4; ++r) {
                const int u_loc = g * 32 + w * 16 + g4 * 4 + r;
                const bool valid = (u_loc < U);
                const int tu = valid ? rows_tu[s * 2048 + u_loc] : 0;
                const int t_ = tu >> 5;
                int tt = t_ - ts0;
                tt = (tt < 0) ? 0 : tt;
                const unsigned long long s4 = slot4_s[tt];
                const int myslot = (int)((s4 >> (4 * n16)) & 15);
                const int expsl  = u_loc - rbase_s[tt];
                const bool match = valid && (myslot == expsl);
                const float sc = acc[r] + bf2f(mask_s[n16][tt]);
                const float wv = match ? __expf(sc) : 0.f;
                l_acc += wv;
                wout[r] = f2bf(wv);
            }
            const int wc = w * 16 + g4 * 4;
            *(unsigned*)&Wt[buf][n16][wc]     = (unsigned)wout[0] | ((unsigned)wout[1] << 16);
            *(unsigned*)&Wt[buf][n16][wc + 2] = (unsigned)wout[2] | ((unsigned)wout[3] << 16);
        } else if (g > 0) {
            // ---- PV(g-1) from the other parity ----
            pv_step(buf ^ 1, w, n16, g4, Wt, Vb, accO);
        }
        __syncthreads();   // barrier2: Wt[buf] ready; PV(g-1) done
    }
    if (G > 0 && w >= 2) {
        pv_step((G - 1) & 1, w, n16, g4, Wt, Vb, accO);
    }
#undef LOADR
#undef PACK8

    // ---- l reduction (waves 0,1) ----
    if (w < 2) {
        l_acc += __shfl_xor(l_acc, 16, 64);
        l_acc += __shfl_xor(l_acc, 32, 64);
        if (l < 16) ls[w][n16] = l_acc;
    }
    __syncthreads();
    if (tid < 16)
        pl[((size_t)tid * HH + h) * NSP + s] = ls[0][tid] + ls[1][tid];

    // ---- O partial write (C/D layout: col=n16=d-local, row=g4*4+r=b) ----
    if (w >= 2) {
        #pragma unroll
        for (int dt = 0; dt < 4; ++dt) {
            const int d = ((w - 2) * 4 + dt) * 16 + n16;
            #pragma unroll
            for (int r = 0; r < 4; ++r) {
                const int b = g4 * 4 + r;
                po[((size_t)(b * HH + h) * NSP + s) * DD + d] = accO[dt][r];
            }
        }
    }
}

// ---------------------------------------------------------------------------
// Kernel 3: merge the NSP partials per (b,h) — plain sum + normalize.
// ---------------------------------------------------------------------------
__global__ __launch_bounds__(128)
void attn_reduce_kernel(const float* __restrict__ pl,
                        const float* __restrict__ po,
                        float* __restrict__ out) {
    const int bh = blockIdx.x;
    const int d  = threadIdx.x;
    float l = 0.f, o = 0.f;
    #pragma unroll 8
    for (int s = 0; s < NSP; ++s) {
        l += pl[(size_t)bh * NSP + s];
        o += po[((size_t)bh * NSP + s) * DD + d];
    }
    out[(size_t)bh * DD + d] = o / l;
}

// ---------------------------------------------------------------------------
extern "C" void kernel_launch(void* const* d_in, const int* in_sizes, int n_in,
                              void* d_out, int out_size, void* d_ws, size_t ws_size,
                              hipStream_t stream) {
    const float* q    = (const float*)d_in[0];
    const float* knew = (const float*)d_in[1];
    const float* vnew = (const float*)d_in[2];
    const float* kc   = (const float*)d_in[3];
    const float* vc   = (const float*)d_in[4];
    const int*   bidx = (const int*)d_in[5];
    const float* mask = (const float*)d_in[6];
    const int*   offp = (const int*)d_in[7];

    char* ws = (char*)d_ws;
    int*                trace_tb = (int*)(ws);                          // 131072
    unsigned long long* slot4    = (unsigned long long*)(ws + 131072);  // 16384
    int*                rowstart = (int*)(ws + 147456);                 // 8192
    int*                rows_tu  = (int*)(ws + 155648);                 // 196608
    int*                ucnt_g   = (int*)(ws + 352256);                 // 512
    float*              pl       = (float*)(ws + 352768);               // 49152
    float*              po       = (float*)(ws + 401920);               // 6291456

    hipLaunchKernelGGL(trace_kernel, dim3(1), dim3(1024), 0, stream,
                       bidx, offp, trace_tb, slot4, rowstart, rows_tu,
                       ucnt_g);
    hipLaunchKernelGGL(attn_split_kernel, dim3(HH * NSP), dim3(256), 0, stream,
                       q, knew, vnew, kc, vc, mask,
                       slot4, rowstart, rows_tu, ucnt_g, offp,
                       pl, po);
    hipLaunchKernelGGL(attn_reduce_kernel, dim3(BEAMS * HH), dim3(128), 0, stream,
                       pl, po, (float*)d_out);
}